// Round 6
// baseline (141.630 us; speedup 1.0000x reference)
//
#include <hip/hip_runtime.h>
#include <hip/hip_bf16.h>
#include <math.h>

#define N 4096
#define D 1024
#define NINST 8
#define NGROUP (N / NINST)
#define ALPHA 20.0f
#define MARGIN 0.5f

typedef __attribute__((ext_vector_type(8))) short bf16x8;
typedef __attribute__((ext_vector_type(4))) float f32x4;

__device__ __forceinline__ unsigned fkey(float f) {
    int b = __float_as_int(f);
    return (b >= 0) ? ((unsigned)b | 0x80000000u) : ~(unsigned)b;
}
__device__ __forceinline__ float fdec(unsigned u) {
    int b = (u & 0x80000000u) ? (int)(u ^ 0x80000000u) : ~(int)u;
    return __int_as_float(b);
}

// stable fast softplus: log1p(exp(x)) = max(x,0) + log(1 + exp(-|x|))
__device__ __forceinline__ float softplus(float x) {
    float z = __expf(-fabsf(x));
    return fmaxf(x, 0.0f) + __logf(1.0f + z);
}

// async global -> LDS, 16 bytes per lane (lds dest: wave-uniform base + lane*16)
__device__ __forceinline__ void gld16(const void* g, void* l) {
    __builtin_amdgcn_global_load_lds(
        (const __attribute__((address_space(1))) void*)g,
        (__attribute__((address_space(3))) void*)l, 16, 0, 0);
}

// ---------------- K1: per-group normalize + bf16 write + exact fp32 8x8 Gram ----------------
__global__ __launch_bounds__(256) void k_normpos(const float* __restrict__ in,
                                                 ushort* __restrict__ xn,
                                                 float* __restrict__ pos_sims,
                                                 float* __restrict__ min_pos,
                                                 unsigned* __restrict__ gmax,
                                                 float* __restrict__ accum,
                                                 unsigned* __restrict__ cnt) {
    __shared__ float4 srows4[2048];    // 8 rows x 256 float4 = 32 KB
    __shared__ float spart[8][4];
    __shared__ float sinv[8];
    __shared__ float sg[8][8];

    int g = blockIdx.x;
    int t = threadIdx.x;
    int lane = t & 63, wid = t >> 6;

    if (g == 0 && t == 0) { *gmax = 0u; *accum = 0.f; *cnt = 0u; }

    const float4* in4 = (const float4*)in;
    #pragma unroll
    for (int i = 0; i < 8; ++i) {
        float4 v = in4[(size_t)g * 2048 + i * 256 + t];
        srows4[i * 256 + t] = v;
        float ss = v.x * v.x + v.y * v.y + v.z * v.z + v.w * v.w;
        #pragma unroll
        for (int off = 1; off < 64; off <<= 1) ss += __shfl_xor(ss, off);
        if (lane == 0) spart[i][wid] = ss;
    }
    __syncthreads();
    if (t < 8) sinv[t] = rsqrtf(spart[t][0] + spart[t][1] + spart[t][2] + spart[t][3]);
    __syncthreads();

    #pragma unroll
    for (int i = 0; i < 8; ++i) {
        float4 v = srows4[i * 256 + t];
        float inv = sinv[i];
        ushort4 o;
        __hip_bfloat16 h;
        h = __float2bfloat16(v.x * inv); o.x = *(ushort*)&h;
        h = __float2bfloat16(v.y * inv); o.y = *(ushort*)&h;
        h = __float2bfloat16(v.z * inv); o.z = *(ushort*)&h;
        h = __float2bfloat16(v.w * inv); o.w = *(ushort*)&h;
        ((ushort4*)(xn + (size_t)(g * 8 + i) * D))[t] = o;
    }

    int pair = t >> 2, a = pair >> 3, b = pair & 7, slice = t & 3;
    const float4* pa = srows4 + a * 256 + slice * 64;
    const float4* pb = srows4 + b * 256 + slice * 64;
    float s = 0.f;
    #pragma unroll 8
    for (int i = 0; i < 64; ++i) {
        float4 x = pa[i], y = pb[i];
        s += x.x * y.x + x.y * y.y + x.z * y.z + x.w * y.w;
    }
    s += __shfl_xor(s, 1);
    s += __shfl_xor(s, 2);
    if (slice == 0) sg[a][b] = s * sinv[a] * sinv[b];
    __syncthreads();
    if (t < 8) {
        float mn = 1e30f;
        int idx = 0;
        #pragma unroll
        for (int b2 = 0; b2 < 8; ++b2) {
            if (b2 == t) continue;
            float v = sg[t][b2];
            mn = fminf(mn, v);
            pos_sims[(size_t)(g * 8 + t) * 8 + idx] = v;
            ++idx;
        }
        min_pos[g * 8 + t] = mn;
    }
}

// ---------------- K2: symmetric MFMA sim tiles, 4-deep counted-vmcnt pipeline ----------------
// grid 528 = 32*33/2 tiles (rt<=ct); block 256 = 4 waves in 2x2; 128x128 tile; BK=32.
// 4 LDS buffer pairs; stages 0-2 prefetched; per iter: vmcnt(8) [counted, never 0
// in main loop] -> s_barrier -> issue stage it+3 -> ds_read + 16 MFMA.
// All tiles (incl. diag) stage 4 loads/wave/stage -> uniform vmcnt counts.
__global__ __launch_bounds__(256) void k_neg(const ushort* __restrict__ xn,
                                             const float* __restrict__ min_pos,
                                             float* __restrict__ sum_part,
                                             int* __restrict__ cnt_part,
                                             float* __restrict__ max_part,
                                             unsigned* __restrict__ gmax) {
    __shared__ ushort sA[4][128 * 32];   // 32 KB
    __shared__ ushort sB[4][128 * 32];   // 32 KB
    __shared__ float sMinA[128];
    __shared__ float sMinB[128];

    // decode triangular tile index (rt, ct), ct >= rt
    int bid = blockIdx.x;
    int rt = 0, rem = bid;
    while (rem >= 32 - rt) { rem -= 32 - rt; ++rt; }
    int ct = rt + rem;
    bool diag = (rt == ct);

    int R0 = rt * 128, C0 = ct * 128;
    int t = threadIdx.x, lane = t & 63, wid = t >> 6;
    int wr = wid >> 1, wc = wid & 1;

    // sMin loads issued BEFORE staging (their vmcnt slots retire first; counted
    // waits below remain correct since vmcnt(8) retires all older ops).
    if (t < 128) { sMinA[t] = min_pos[R0 + t]; sMinB[t] = min_pos[C0 + t]; }

    int srow = t >> 2;
    int skoff = (t & 3) * 8;
    const ushort* gA0 = xn + (size_t)(R0 + srow) * D + skoff;
    const ushort* gA1 = xn + (size_t)(R0 + 64 + srow) * D + skoff;
    const ushort* gB0 = xn + (size_t)(C0 + srow) * D + skoff;   // == gA0 when diag
    const ushort* gB1 = xn + (size_t)(C0 + 64 + srow) * D + skoff;
    unsigned wbase = (unsigned)wid * 1024;   // 64 lanes * 16B per wave

    int lrow = lane & 15;
    int kgrp = lane >> 4;    // 0..3 -> k-octet

    f32x4 zero = {0.f, 0.f, 0.f, 0.f};
    f32x4 acc[4][4];
    #pragma unroll
    for (int m = 0; m < 4; ++m)
        #pragma unroll
        for (int n = 0; n < 4; ++n) acc[m][n] = zero;

    #define STAGE(buf, k0)                                        \
        do {                                                      \
            char* lA_ = (char*)sA[buf];                           \
            char* lB_ = (char*)sB[buf];                           \
            gld16(gA0 + (k0), lA_ + wbase);                       \
            gld16(gA1 + (k0), lA_ + 4096 + wbase);                \
            gld16(gB0 + (k0), lB_ + wbase);                       \
            gld16(gB1 + (k0), lB_ + 4096 + wbase);                \
        } while (0)

    STAGE(0, 0);
    STAGE(1, 32);
    STAGE(2, 64);

    for (int it = 0; it < 32; ++it) {
        // counted wait: retire stage `it` (2 stages stay in flight), then sync.
        if (it < 30)       asm volatile("s_waitcnt vmcnt(8)" ::: "memory");
        else if (it == 30) asm volatile("s_waitcnt vmcnt(4)" ::: "memory");
        else               asm volatile("s_waitcnt vmcnt(0)" ::: "memory");
        __builtin_amdgcn_s_barrier();

        // stage target (it+3)&3 == (it-1)&3: its readers all passed this barrier.
        if (it < 29) STAGE((it + 3) & 3, (it + 3) * 32);

        int cb = it & 3;
        const ushort* fA = sA[cb] + (size_t)(wr * 64 + lrow) * 32 + kgrp * 8;
        const ushort* fB = sB[cb] + (size_t)(wc * 64 + lrow) * 32 + kgrp * 8;
        bf16x8 a[4], b[4];
        #pragma unroll
        for (int m = 0; m < 4; ++m)
            a[m] = *(const bf16x8*)(fA + (size_t)m * 16 * 32);
        #pragma unroll
        for (int n = 0; n < 4; ++n)
            b[n] = *(const bf16x8*)(fB + (size_t)n * 16 * 32);
        #pragma unroll
        for (int m = 0; m < 4; ++m)
            #pragma unroll
            for (int n = 0; n < 4; ++n)
                acc[m][n] = __builtin_amdgcn_mfma_f32_16x16x32_bf16(a[m], b[n], acc[m][n], 0, 0, 0);
    }
    #undef STAGE
    __syncthreads();   // sMin LDS visibility + loop exit sync

    // ---- epilogue: row-band stats; col-band (transpose) stats for off-diag ----
    float allmax = -1e30f;
    int cbase = C0 + wc * 64;
    int pcRow = ct * 2 + wc;     // row-stat slot
    int pcCol = rt * 2 + wr;     // col-stat slot (transpose contribution)

    float thB[4];
    #pragma unroll
    for (int n = 0; n < 4; ++n) thB[n] = sMinB[wc * 64 + n * 16 + lrow] - 0.05f;

    float colS[4] = {0.f, 0.f, 0.f, 0.f};
    float colM[4] = {-1e30f, -1e30f, -1e30f, -1e30f};
    int   colC[4] = {0, 0, 0, 0};

    #pragma unroll
    for (int m = 0; m < 4; ++m) {
        #pragma unroll
        for (int reg = 0; reg < 4; ++reg) {
            int lr = wr * 64 + m * 16 + kgrp * 4 + reg;   // local row in [0,128)
            int grow = R0 + lr;
            float th = sMinA[lr] - 0.05f;
            int gi = grow >> 3;
            float rs = 0.f, rm = -1e30f;
            int rc = 0;
            #pragma unroll
            for (int n = 0; n < 4; ++n) {
                int gcol = cbase + n * 16 + lrow;
                float s = acc[m][n][reg];
                allmax = fmaxf(allmax, s);
                if ((gcol >> 3) != gi) {
                    float e = softplus(ALPHA * (s - MARGIN));
                    rm = fmaxf(rm, s);
                    if (s > th) { rs += e; rc += 1; }
                    if (!diag) {
                        colM[n] = fmaxf(colM[n], s);
                        if (s > thB[n]) { colS[n] += e; colC[n] += 1; }
                    }
                }
            }
            #pragma unroll
            for (int off = 1; off < 16; off <<= 1) {
                rs += __shfl_xor(rs, off);
                rc += __shfl_xor(rc, off);
                rm = fmaxf(rm, __shfl_xor(rm, off));
            }
            if (lrow == 0) {
                sum_part[(size_t)grow * 64 + pcRow] = rs;
                cnt_part[(size_t)grow * 64 + pcRow] = rc;
                max_part[(size_t)grow * 64 + pcRow] = rm;
            }
        }
    }

    if (!diag) {
        #pragma unroll
        for (int n = 0; n < 4; ++n) {
            float cs = colS[n], cm = colM[n];
            int cc = colC[n];
            cs += __shfl_xor(cs, 16); cs += __shfl_xor(cs, 32);
            cc += __shfl_xor(cc, 16); cc += __shfl_xor(cc, 32);
            cm = fmaxf(cm, __shfl_xor(cm, 16));
            cm = fmaxf(cm, __shfl_xor(cm, 32));
            if (kgrp == 0) {
                int gcol = cbase + n * 16 + lrow;
                sum_part[(size_t)gcol * 64 + pcCol] = cs;
                cnt_part[(size_t)gcol * 64 + pcCol] = cc;
                max_part[(size_t)gcol * 64 + pcCol] = cm;
            }
        }
    }

    #pragma unroll
    for (int off = 1; off < 64; off <<= 1) allmax = fmaxf(allmax, __shfl_xor(allmax, off));
    if (lane == 0) atomicMax(gmax, fkey(allmax));
}

// ---------------- K3: per-row combine + last-block final mean ----------------
__global__ __launch_bounds__(256) void k_rowfinal(const float* __restrict__ sum_part,
                                                  const int* __restrict__ cnt_part,
                                                  const float* __restrict__ max_part,
                                                  const float* __restrict__ pos_sims,
                                                  const float* __restrict__ min_pos,
                                                  const unsigned* __restrict__ gmax,
                                                  float* __restrict__ accum,
                                                  unsigned* __restrict__ cnt,
                                                  float* __restrict__ out) {
    __shared__ float sloss[4];
    int row = blockIdx.x * 4 + (threadIdx.x >> 6);
    int lane = threadIdx.x & 63;
    float ns = sum_part[(size_t)row * 64 + lane];
    int nc = cnt_part[(size_t)row * 64 + lane];
    float nm = max_part[(size_t)row * 64 + lane];
    #pragma unroll
    for (int off = 1; off < 64; off <<= 1) {
        ns += __shfl_xor(ns, off);
        nc += __shfl_xor(nc, off);
        nm = fmaxf(nm, __shfl_xor(nm, off));
    }
    if (lane == 0) {
        float base = fmaxf(fdec(*gmax) - 0.1f, MARGIN + 0.2f);
        float neg_loss = (nc > 0) ? ns / (float)nc : softplus(ALPHA * (nm - MARGIN));
        float ps = 0.f;
        int pcnt = 0;
        float mn = min_pos[row];
        #pragma unroll
        for (int i = 0; i < NINST - 1; ++i) {
            float s = pos_sims[(size_t)row * 8 + i];
            if (s < base) { ps += softplus(-2.0f * (s - MARGIN)); pcnt++; }
        }
        float pos_loss = (pcnt > 0) ? ps / (float)pcnt : softplus(-2.0f * (mn - MARGIN));
        sloss[threadIdx.x >> 6] = pos_loss + neg_loss;
    }
    __syncthreads();
    if (threadIdx.x == 0) {
        float bs = sloss[0] + sloss[1] + sloss[2] + sloss[3];
        atomicAdd(accum, bs);
        __threadfence();
        unsigned old = atomicAdd(cnt, 1u);
        if (old == gridDim.x - 1) {
            __threadfence();
            float tot = atomicAdd(accum, 0.0f);   // final sum (all adds done)
            out[0] = tot / (float)N;
        }
    }
}

extern "C" void kernel_launch(void* const* d_in, const int* in_sizes, int n_in,
                              void* d_out, int out_size, void* d_ws, size_t ws_size,
                              hipStream_t stream) {
    const float* in = (const float*)d_in[0];
    float* out = (float*)d_out;

    char* ws = (char*)d_ws;
    ushort*  xn       = (ushort*)(ws);                          // 8 MB
    float*   min_pos  = (float*)(ws + 8388608 + 16384);         // 16 KB
    float*   pos_sims = (float*)(ws + 8388608 + 32768);         // 128 KB
    float*   sum_part = (float*)(ws + 8388608 + 32768 + 131072);            // 1 MB
    float*   max_part = (float*)(ws + 8388608 + 32768 + 131072 + 1048576);  // 1 MB
    int*     cnt_part = (int*)  (ws + 8388608 + 32768 + 131072 + 2097152);  // 1 MB
    unsigned* gmax    = (unsigned*)(ws + 8388608 + 32768 + 131072 + 3145728 + 16384);
    float*   accum    = (float*)(ws + 8388608 + 32768 + 131072 + 3145728 + 16384 + 64);
    unsigned* cnt     = (unsigned*)(ws + 8388608 + 32768 + 131072 + 3145728 + 16384 + 128);

    k_normpos<<<NGROUP, 256, 0, stream>>>(in, xn, pos_sims, min_pos, gmax, accum, cnt);
    k_neg<<<528, 256, 0, stream>>>(xn, min_pos, sum_part, cnt_part, max_part, gmax);
    k_rowfinal<<<N / 4, 256, 0, stream>>>(sum_part, cnt_part, max_part, pos_sims, min_pos,
                                          gmax, accum, cnt, out);
}

// Round 7
// 125.102 us; speedup vs baseline: 1.1321x; 1.1321x over previous
//
#include <hip/hip_runtime.h>
#include <hip/hip_bf16.h>
#include <math.h>

#define N 4096
#define D 1024
#define NINST 8
#define NGROUP (N / NINST)
#define ALPHA 20.0f
#define MARGIN 0.5f

typedef __attribute__((ext_vector_type(8))) short bf16x8;
typedef __attribute__((ext_vector_type(4))) float f32x4;

__device__ __forceinline__ unsigned fkey(float f) {
    int b = __float_as_int(f);
    return (b >= 0) ? ((unsigned)b | 0x80000000u) : ~(unsigned)b;
}
__device__ __forceinline__ float fdec(unsigned u) {
    int b = (u & 0x80000000u) ? (int)(u ^ 0x80000000u) : ~(int)u;
    return __int_as_float(b);
}

// stable fast softplus: log1p(exp(x)) = max(x,0) + log(1 + exp(-|x|))
__device__ __forceinline__ float softplus(float x) {
    float z = __expf(-fabsf(x));
    return fmaxf(x, 0.0f) + __logf(1.0f + z);
}

// async global -> LDS, 16 bytes per lane (lds dest: wave-uniform base + lane*16)
__device__ __forceinline__ void gld16(const void* g, void* l) {
    __builtin_amdgcn_global_load_lds(
        (const __attribute__((address_space(1))) void*)g,
        (__attribute__((address_space(3))) void*)l, 16, 0, 0);
}

// ---------------- K1: per-group normalize + bf16 write + exact fp32 8x8 Gram ----------------
__global__ __launch_bounds__(256) void k_normpos(const float* __restrict__ in,
                                                 ushort* __restrict__ xn,
                                                 float* __restrict__ pos_sims,
                                                 float* __restrict__ min_pos,
                                                 unsigned* __restrict__ gmax,
                                                 float* __restrict__ accum,
                                                 unsigned* __restrict__ cnt) {
    __shared__ float4 srows4[2048];    // 8 rows x 256 float4 = 32 KB
    __shared__ float spart[8][4];
    __shared__ float sinv[8];
    __shared__ float sg[8][8];

    int g = blockIdx.x;
    int t = threadIdx.x;
    int lane = t & 63, wid = t >> 6;

    if (g == 0 && t == 0) { *gmax = 0u; *accum = 0.f; *cnt = 0u; }

    const float4* in4 = (const float4*)in;
    #pragma unroll
    for (int i = 0; i < 8; ++i) {
        float4 v = in4[(size_t)g * 2048 + i * 256 + t];
        srows4[i * 256 + t] = v;
        float ss = v.x * v.x + v.y * v.y + v.z * v.z + v.w * v.w;
        #pragma unroll
        for (int off = 1; off < 64; off <<= 1) ss += __shfl_xor(ss, off);
        if (lane == 0) spart[i][wid] = ss;
    }
    __syncthreads();
    if (t < 8) sinv[t] = rsqrtf(spart[t][0] + spart[t][1] + spart[t][2] + spart[t][3]);
    __syncthreads();

    #pragma unroll
    for (int i = 0; i < 8; ++i) {
        float4 v = srows4[i * 256 + t];
        float inv = sinv[i];
        ushort4 o;
        __hip_bfloat16 h;
        h = __float2bfloat16(v.x * inv); o.x = *(ushort*)&h;
        h = __float2bfloat16(v.y * inv); o.y = *(ushort*)&h;
        h = __float2bfloat16(v.z * inv); o.z = *(ushort*)&h;
        h = __float2bfloat16(v.w * inv); o.w = *(ushort*)&h;
        ((ushort4*)(xn + (size_t)(g * 8 + i) * D))[t] = o;
    }

    int pair = t >> 2, a = pair >> 3, b = pair & 7, slice = t & 3;
    const float4* pa = srows4 + a * 256 + slice * 64;
    const float4* pb = srows4 + b * 256 + slice * 64;
    float s = 0.f;
    #pragma unroll 8
    for (int i = 0; i < 64; ++i) {
        float4 x = pa[i], y = pb[i];
        s += x.x * y.x + x.y * y.y + x.z * y.z + x.w * y.w;
    }
    s += __shfl_xor(s, 1);
    s += __shfl_xor(s, 2);
    if (slice == 0) sg[a][b] = s * sinv[a] * sinv[b];
    __syncthreads();
    if (t < 8) {
        float mn = 1e30f;
        int idx = 0;
        #pragma unroll
        for (int b2 = 0; b2 < 8; ++b2) {
            if (b2 == t) continue;
            float v = sg[t][b2];
            mn = fminf(mn, v);
            pos_sims[(size_t)(g * 8 + t) * 8 + idx] = v;
            ++idx;
        }
        min_pos[g * 8 + t] = mn;
    }
}

// ---------------- K2: symmetric MFMA sim tiles, 8 waves/block for TLP ----------------
// grid 528 = 32*33/2 tiles (rt<=ct); block 512 = 8 waves in 2x4; 128x128 tile; BK=32.
// 2 blocks/CU * 8 waves = 16 waves/CU (R2-level TLP at half the work).
// Off-diagonal tiles emit row-band stats AND col-band (transpose) stats.
// Partials combined across waves in LDS -> 32 slots/row: slot q of row r (band b)
// comes from tile (b,q) row-stats if q>=b, else tile (q,b) col-stats.
__global__ __launch_bounds__(512) void k_neg(const ushort* __restrict__ xn,
                                             const float* __restrict__ min_pos,
                                             float* __restrict__ sum_part,
                                             int* __restrict__ cnt_part,
                                             float* __restrict__ max_part,
                                             unsigned* __restrict__ gmax) {
    __shared__ ushort sA[2][128 * 32];   // 16 KB
    __shared__ ushort sB[2][128 * 32];   // 16 KB
    __shared__ float sMinA[128];
    __shared__ float sMinB[128];
    __shared__ float sRS[4][128]; __shared__ int sRC[4][128]; __shared__ float sRM[4][128];
    __shared__ float sCS[2][128]; __shared__ int sCC[2][128]; __shared__ float sCM[2][128];

    // decode triangular tile index (rt, ct), ct >= rt
    int bid = blockIdx.x;
    int rt = 0, rem = bid;
    while (rem >= 32 - rt) { rem -= 32 - rt; ++rt; }
    int ct = rt + rem;
    bool diag = (rt == ct);

    int R0 = rt * 128, C0 = ct * 128;
    int t = threadIdx.x, lane = t & 63, wid = t >> 6;   // wid 0..7
    int wr = wid >> 2, wc = wid & 3;                    // wave-grid 2x4

    if (t < 128) { sMinA[t] = min_pos[R0 + t]; sMinB[t] = min_pos[C0 + t]; }

    // staging: 512 threads x 16B = full 128x32 bf16 panel in ONE gld16 per operand.
    // thread t: row = t>>2, k-octet = (t&3)*8; LDS linear byte offset = t*16.
    int srow = t >> 2;
    int skoff = (t & 3) * 8;
    const ushort* gA = xn + (size_t)(R0 + srow) * D + skoff;
    const ushort* gB = xn + (size_t)(C0 + srow) * D + skoff;
    unsigned wbase = (unsigned)wid * 1024;

    int lrow = lane & 15;
    int kgrp = lane >> 4;    // 0..3 -> k-octet

    f32x4 zero = {0.f, 0.f, 0.f, 0.f};
    f32x4 acc[4][2];
    #pragma unroll
    for (int m = 0; m < 4; ++m)
        #pragma unroll
        for (int n = 0; n < 2; ++n) acc[m][n] = zero;

    #define STAGE(buf, k0)                                  \
        do {                                                \
            gld16(gA + (k0), (char*)sA[buf] + wbase);       \
            gld16(gB + (k0), (char*)sB[buf] + wbase);       \
        } while (0)

    STAGE(0, 0);
    __syncthreads();

    int cur = 0;
    for (int it = 0; it < 32; ++it) {
        if (it + 1 < 32) STAGE(cur ^ 1, (it + 1) * 32);   // prefetch next tile

        const ushort* sBb = diag ? sA[cur] : sB[cur];
        const ushort* fA = sA[cur] + (size_t)(wr * 64 + lrow) * 32 + kgrp * 8;
        const ushort* fB = sBb + (size_t)(wc * 32 + lrow) * 32 + kgrp * 8;
        bf16x8 a[4], b[2];
        #pragma unroll
        for (int m = 0; m < 4; ++m)
            a[m] = *(const bf16x8*)(fA + (size_t)m * 16 * 32);
        #pragma unroll
        for (int n = 0; n < 2; ++n)
            b[n] = *(const bf16x8*)(fB + (size_t)n * 16 * 32);
        #pragma unroll
        for (int m = 0; m < 4; ++m)
            #pragma unroll
            for (int n = 0; n < 2; ++n)
                acc[m][n] = __builtin_amdgcn_mfma_f32_16x16x32_bf16(a[m], b[n], acc[m][n], 0, 0, 0);

        __syncthreads();
        cur ^= 1;
    }
    #undef STAGE

    // ---- epilogue: per-wave partials -> LDS combine -> 32-slot global writes ----
    float allmax = -1e30f;
    int cwbase = C0 + wc * 32;

    float thB[2];
    #pragma unroll
    for (int n = 0; n < 2; ++n) thB[n] = sMinB[wc * 32 + n * 16 + lrow] - 0.05f;

    float colS[2] = {0.f, 0.f};
    float colM[2] = {-1e30f, -1e30f};
    int   colC[2] = {0, 0};

    #pragma unroll
    for (int m = 0; m < 4; ++m) {
        #pragma unroll
        for (int reg = 0; reg < 4; ++reg) {
            int lr = wr * 64 + m * 16 + kgrp * 4 + reg;   // local row in [0,128)
            int grow = R0 + lr;
            float th = sMinA[lr] - 0.05f;
            int gi = grow >> 3;
            float rs = 0.f, rm = -1e30f;
            int rc = 0;
            #pragma unroll
            for (int n = 0; n < 2; ++n) {
                int gcol = cwbase + n * 16 + lrow;
                float s = acc[m][n][reg];
                allmax = fmaxf(allmax, s);
                if ((gcol >> 3) != gi) {
                    float e = softplus(ALPHA * (s - MARGIN));
                    rm = fmaxf(rm, s);
                    if (s > th) { rs += e; rc += 1; }
                    if (!diag) {
                        colM[n] = fmaxf(colM[n], s);
                        if (s > thB[n]) { colS[n] += e; colC[n] += 1; }
                    }
                }
            }
            // reduce across the 16 col-lanes (same kgrp group)
            #pragma unroll
            for (int off = 1; off < 16; off <<= 1) {
                rs += __shfl_xor(rs, off);
                rc += __shfl_xor(rc, off);
                rm = fmaxf(rm, __shfl_xor(rm, off));
            }
            if (lrow == 0) { sRS[wc][lr] = rs; sRC[wc][lr] = rc; sRM[wc][lr] = rm; }
        }
    }

    if (!diag) {
        // col stats: reduce across the 4 kgrp lane-groups (lanes l, l^16, l^32, l^48)
        #pragma unroll
        for (int n = 0; n < 2; ++n) {
            float cs = colS[n], cm = colM[n];
            int cc = colC[n];
            cs += __shfl_xor(cs, 16); cs += __shfl_xor(cs, 32);
            cc += __shfl_xor(cc, 16); cc += __shfl_xor(cc, 32);
            cm = fmaxf(cm, __shfl_xor(cm, 16));
            cm = fmaxf(cm, __shfl_xor(cm, 32));
            if (kgrp == 0) {
                int lc = wc * 32 + n * 16 + lrow;
                sCS[wr][lc] = cs; sCC[wr][lc] = cc; sCM[wr][lc] = cm;
            }
        }
    }
    __syncthreads();

    if (t < 128) {
        int r = t;
        float rs = sRS[0][r] + sRS[1][r] + sRS[2][r] + sRS[3][r];
        int   rc = sRC[0][r] + sRC[1][r] + sRC[2][r] + sRC[3][r];
        float rm = fmaxf(fmaxf(sRM[0][r], sRM[1][r]), fmaxf(sRM[2][r], sRM[3][r]));
        sum_part[(size_t)(R0 + r) * 32 + ct] = rs;
        cnt_part[(size_t)(R0 + r) * 32 + ct] = rc;
        max_part[(size_t)(R0 + r) * 32 + ct] = rm;
    } else if (t < 256 && !diag) {
        int c = t - 128;
        float cs = sCS[0][c] + sCS[1][c];
        int   cc = sCC[0][c] + sCC[1][c];
        float cm = fmaxf(sCM[0][c], sCM[1][c]);
        sum_part[(size_t)(C0 + c) * 32 + rt] = cs;
        cnt_part[(size_t)(C0 + c) * 32 + rt] = cc;
        max_part[(size_t)(C0 + c) * 32 + rt] = cm;
    }

    #pragma unroll
    for (int off = 1; off < 64; off <<= 1) allmax = fmaxf(allmax, __shfl_xor(allmax, off));
    if (lane == 0) atomicMax(gmax, fkey(allmax));
}

// ---------------- K3: per-row combine (32 slots, 32 lanes/row) + last-block mean ----------------
__global__ __launch_bounds__(256) void k_rowfinal(const float* __restrict__ sum_part,
                                                  const int* __restrict__ cnt_part,
                                                  const float* __restrict__ max_part,
                                                  const float* __restrict__ pos_sims,
                                                  const float* __restrict__ min_pos,
                                                  const unsigned* __restrict__ gmax,
                                                  float* __restrict__ accum,
                                                  unsigned* __restrict__ cnt,
                                                  float* __restrict__ out) {
    __shared__ float sloss[8];
    int row = blockIdx.x * 8 + (threadIdx.x >> 5);
    int l = threadIdx.x & 31;
    float ns = sum_part[(size_t)row * 32 + l];
    int nc = cnt_part[(size_t)row * 32 + l];
    float nm = max_part[(size_t)row * 32 + l];
    #pragma unroll
    for (int off = 1; off < 32; off <<= 1) {
        ns += __shfl_xor(ns, off);
        nc += __shfl_xor(nc, off);
        nm = fmaxf(nm, __shfl_xor(nm, off));
    }
    if (l == 0) {
        float base = fmaxf(fdec(*gmax) - 0.1f, MARGIN + 0.2f);
        float neg_loss = (nc > 0) ? ns / (float)nc : softplus(ALPHA * (nm - MARGIN));
        float ps = 0.f;
        int pcnt = 0;
        float mn = min_pos[row];
        #pragma unroll
        for (int i = 0; i < NINST - 1; ++i) {
            float s = pos_sims[(size_t)row * 8 + i];
            if (s < base) { ps += softplus(-2.0f * (s - MARGIN)); pcnt++; }
        }
        float pos_loss = (pcnt > 0) ? ps / (float)pcnt : softplus(-2.0f * (mn - MARGIN));
        sloss[threadIdx.x >> 5] = pos_loss + neg_loss;
    }
    __syncthreads();
    if (threadIdx.x == 0) {
        float bs = 0.f;
        #pragma unroll
        for (int i = 0; i < 8; ++i) bs += sloss[i];
        atomicAdd(accum, bs);
        __threadfence();
        unsigned old = atomicAdd(cnt, 1u);
        if (old == gridDim.x - 1) {
            __threadfence();
            float tot = atomicAdd(accum, 0.0f);   // final sum (all adds done)
            out[0] = tot / (float)N;
        }
    }
}

extern "C" void kernel_launch(void* const* d_in, const int* in_sizes, int n_in,
                              void* d_out, int out_size, void* d_ws, size_t ws_size,
                              hipStream_t stream) {
    const float* in = (const float*)d_in[0];
    float* out = (float*)d_out;

    char* ws = (char*)d_ws;
    ushort*  xn       = (ushort*)(ws);                          // 8 MB
    float*   min_pos  = (float*)(ws + 8388608 + 16384);         // 16 KB
    float*   pos_sims = (float*)(ws + 8388608 + 32768);         // 128 KB
    float*   sum_part = (float*)(ws + 8388608 + 32768 + 131072);            // 512 KB
    float*   max_part = (float*)(ws + 8388608 + 32768 + 131072 + 524288);   // 512 KB
    int*     cnt_part = (int*)  (ws + 8388608 + 32768 + 131072 + 1048576);  // 512 KB
    unsigned* gmax    = (unsigned*)(ws + 8388608 + 32768 + 131072 + 1572864);
    float*   accum    = (float*)(ws + 8388608 + 32768 + 131072 + 1572864 + 64);
    unsigned* cnt     = (unsigned*)(ws + 8388608 + 32768 + 131072 + 1572864 + 128);

    k_normpos<<<NGROUP, 256, 0, stream>>>(in, xn, pos_sims, min_pos, gmax, accum, cnt);
    k_neg<<<528, 512, 0, stream>>>(xn, min_pos, sum_part, cnt_part, max_part, gmax);
    k_rowfinal<<<N / 8, 256, 0, stream>>>(sum_part, cnt_part, max_part, pos_sims, min_pos,
                                          gmax, accum, cnt, out);
}

// Round 8
// 120.140 us; speedup vs baseline: 1.1789x; 1.0413x over previous
//
#include <hip/hip_runtime.h>
#include <hip/hip_bf16.h>
#include <math.h>

#define N 4096
#define D 1024
#define NINST 8
#define NGROUP (N / NINST)
#define ALPHA 20.0f
#define MARGIN 0.5f
#define NB 64            // 64-row bands
#define NTILE (NB * (NB + 1) / 2)   // 2080 triangular tiles

typedef __attribute__((ext_vector_type(8))) short bf16x8;
typedef __attribute__((ext_vector_type(4))) float f32x4;

__device__ __forceinline__ unsigned fkey(float f) {
    int b = __float_as_int(f);
    return (b >= 0) ? ((unsigned)b | 0x80000000u) : ~(unsigned)b;
}
__device__ __forceinline__ float fdec(unsigned u) {
    int b = (u & 0x80000000u) ? (int)(u ^ 0x80000000u) : ~(int)u;
    return __int_as_float(b);
}

// stable fast softplus: log1p(exp(x)) = max(x,0) + log(1 + exp(-|x|))
__device__ __forceinline__ float softplus(float x) {
    float z = __expf(-fabsf(x));
    return fmaxf(x, 0.0f) + __logf(1.0f + z);
}

// async global -> LDS, 16 bytes per lane (lds dest: wave-uniform base + lane*16)
__device__ __forceinline__ void gld16(const void* g, void* l) {
    __builtin_amdgcn_global_load_lds(
        (const __attribute__((address_space(1))) void*)g,
        (__attribute__((address_space(3))) void*)l, 16, 0, 0);
}

// ---------------- K1: per-group normalize + bf16 write + exact fp32 8x8 Gram ----------------
// srows4 row stride padded to 257 float4s: spreads Gram-read banks (was 32-way conflict).
__global__ __launch_bounds__(256) void k_normpos(const float* __restrict__ in,
                                                 ushort* __restrict__ xn,
                                                 float* __restrict__ pos_sims,
                                                 float* __restrict__ min_pos,
                                                 unsigned* __restrict__ gmax,
                                                 float* __restrict__ accum,
                                                 unsigned* __restrict__ cnt) {
    __shared__ float4 srows4[8 * 257];   // 32.9 KB
    __shared__ float spart[8][4];
    __shared__ float sinv[8];
    __shared__ float sg[8][8];

    int g = blockIdx.x;
    int t = threadIdx.x;
    int lane = t & 63, wid = t >> 6;

    if (g == 0 && t == 0) { *gmax = 0u; *accum = 0.f; *cnt = 0u; }

    const float4* in4 = (const float4*)in;
    #pragma unroll
    for (int i = 0; i < 8; ++i) {
        float4 v = in4[(size_t)g * 2048 + i * 256 + t];
        srows4[i * 257 + t] = v;
        float ss = v.x * v.x + v.y * v.y + v.z * v.z + v.w * v.w;
        #pragma unroll
        for (int off = 1; off < 64; off <<= 1) ss += __shfl_xor(ss, off);
        if (lane == 0) spart[i][wid] = ss;
    }
    __syncthreads();
    if (t < 8) sinv[t] = rsqrtf(spart[t][0] + spart[t][1] + spart[t][2] + spart[t][3]);
    __syncthreads();

    #pragma unroll
    for (int i = 0; i < 8; ++i) {
        float4 v = srows4[i * 257 + t];
        float inv = sinv[i];
        ushort4 o;
        __hip_bfloat16 h;
        h = __float2bfloat16(v.x * inv); o.x = *(ushort*)&h;
        h = __float2bfloat16(v.y * inv); o.y = *(ushort*)&h;
        h = __float2bfloat16(v.z * inv); o.z = *(ushort*)&h;
        h = __float2bfloat16(v.w * inv); o.w = *(ushort*)&h;
        ((ushort4*)(xn + (size_t)(g * 8 + i) * D))[t] = o;
    }

    int pair = t >> 2, a = pair >> 3, b = pair & 7, slice = t & 3;
    const float4* pa = srows4 + a * 257 + slice * 64;
    const float4* pb = srows4 + b * 257 + slice * 64;
    float s = 0.f;
    #pragma unroll 8
    for (int i = 0; i < 64; ++i) {
        float4 x = pa[i], y = pb[i];
        s += x.x * y.x + x.y * y.y + x.z * y.z + x.w * y.w;
    }
    s += __shfl_xor(s, 1);
    s += __shfl_xor(s, 2);
    if (slice == 0) sg[a][b] = s * sinv[a] * sinv[b];
    __syncthreads();
    if (t < 8) {
        float mn = 1e30f;
        int idx = 0;
        #pragma unroll
        for (int b2 = 0; b2 < 8; ++b2) {
            if (b2 == t) continue;
            float v = sg[t][b2];
            mn = fminf(mn, v);
            pos_sims[(size_t)(g * 8 + t) * 8 + idx] = v;
            ++idx;
        }
        min_pos[g * 8 + t] = mn;
    }
}

// ---------------- K2: symmetric MFMA sim tiles, BARRIER-FREE 1-wave blocks ----------------
// grid 2080 = 64*65/2 triangular 64x64 tiles; block = 1 wave (64 threads).
// Per-wave double-buffered LDS (2 x 4KB x 2 operands) + counted per-wave vmcnt(8):
// no __syncthreads anywhere; loads for stage it+1 stay in flight across iterations.
// Off-diag tiles emit row-band stats AND col-band (transpose) stats.
// Slot q of row r (band rb=r>>6): tile (rb,q) row-stats if q>=rb, else (q,rb) col-stats.
__global__ __launch_bounds__(64, 2) void k_neg(const ushort* __restrict__ xn,
                                               const float* __restrict__ min_pos,
                                               float* __restrict__ sum_part,
                                               int* __restrict__ cnt_part,
                                               float* __restrict__ max_part,
                                               unsigned* __restrict__ gmax) {
    __shared__ ushort sA[2][64 * 32];   // 8 KB
    __shared__ ushort sB[2][64 * 32];   // 8 KB

    // decode triangular tile index (rt, ct), ct >= rt, over 64 bands
    int bid = blockIdx.x;
    int rt = 0, rem = bid;
    while (rem >= NB - rt) { rem -= NB - rt; ++rt; }
    int ct = rt + rem;
    bool diag = (rt == ct);

    int R0 = rt * 64, C0 = ct * 64;
    int l = threadIdx.x;
    int lrow = l & 15;
    int kgrp = l >> 4;    // 0..3 -> k-octet

    // min_pos kept in registers; redistributed later via shfl. Loaded FIRST so the
    // counted vmcnt waits below retire them before stage 0.
    float mA = min_pos[R0 + l];
    float mB = min_pos[C0 + l];

    // staging: per gld16, lane l covers row base+(l>>2), k-octet (l&3); 4 issues per
    // operand cover 64 rows x 32 k. LDS linear: issue j at byte j*1024 (+ lane*16).
    const ushort* gA = xn + (size_t)(R0 + (l >> 2)) * D + (l & 3) * 8;
    const ushort* gB = xn + (size_t)(C0 + (l >> 2)) * D + (l & 3) * 8;

    f32x4 zero = {0.f, 0.f, 0.f, 0.f};
    f32x4 acc[4][4];
    #pragma unroll
    for (int m = 0; m < 4; ++m)
        #pragma unroll
        for (int n = 0; n < 4; ++n) acc[m][n] = zero;

    #define STAGE(buf, k0)                                               \
        do {                                                             \
            char* lA_ = (char*)sA[buf];                                  \
            char* lB_ = (char*)sB[buf];                                  \
            gld16(gA + (k0),            lA_);                            \
            gld16(gA + (k0) + 16 * D,   lA_ + 1024);                     \
            gld16(gA + (k0) + 32 * D,   lA_ + 2048);                     \
            gld16(gA + (k0) + 48 * D,   lA_ + 3072);                     \
            gld16(gB + (k0),            lB_);                            \
            gld16(gB + (k0) + 16 * D,   lB_ + 1024);                     \
            gld16(gB + (k0) + 32 * D,   lB_ + 2048);                     \
            gld16(gB + (k0) + 48 * D,   lB_ + 3072);                     \
        } while (0)

    STAGE(0, 0);     // stage 0 -> buf 0
    STAGE(1, 32);    // stage 1 -> buf 1

    for (int it = 0; it < 32; ++it) {
        // counted per-wave wait: retire stage `it` (8 loads), keep stage it+1 in flight.
        if (it < 31) asm volatile("s_waitcnt vmcnt(8)" ::: "memory");
        else         asm volatile("s_waitcnt vmcnt(0)" ::: "memory");

        int cur = it & 1;
        const ushort* fA = sA[cur] + (size_t)lrow * 32 + kgrp * 8;
        const ushort* fB = sB[cur] + (size_t)lrow * 32 + kgrp * 8;
        bf16x8 a[4], b[4];
        #pragma unroll
        for (int m = 0; m < 4; ++m)
            a[m] = *(const bf16x8*)(fA + (size_t)m * 16 * 32);
        #pragma unroll
        for (int n = 0; n < 4; ++n)
            b[n] = *(const bf16x8*)(fB + (size_t)n * 16 * 32);

        // reads done before the DMA that overwrites this buffer is issued
        asm volatile("s_waitcnt lgkmcnt(0)" ::: "memory");
        if (it <= 29) STAGE(cur, (it + 2) * 32);

        #pragma unroll
        for (int m = 0; m < 4; ++m)
            #pragma unroll
            for (int n = 0; n < 4; ++n)
                acc[m][n] = __builtin_amdgcn_mfma_f32_16x16x32_bf16(a[m], b[n], acc[m][n], 0, 0, 0);
    }
    #undef STAGE

    // ---- epilogue: row-band stats; col-band (transpose) stats for off-diag ----
    float allmax = -1e30f;

    float thB[4];
    #pragma unroll
    for (int n = 0; n < 4; ++n) thB[n] = __shfl(mB, n * 16 + lrow) - 0.05f;

    float colS[4] = {0.f, 0.f, 0.f, 0.f};
    float colM[4] = {-1e30f, -1e30f, -1e30f, -1e30f};
    int   colC[4] = {0, 0, 0, 0};

    #pragma unroll
    for (int m = 0; m < 4; ++m) {
        #pragma unroll
        for (int reg = 0; reg < 4; ++reg) {
            int lr = m * 16 + kgrp * 4 + reg;   // local row in [0,64)
            int grow = R0 + lr;
            float th = __shfl(mA, lr) - 0.05f;
            int gi = grow >> 3;
            float rs = 0.f, rm = -1e30f;
            int rc = 0;
            #pragma unroll
            for (int n = 0; n < 4; ++n) {
                int gcol = C0 + n * 16 + lrow;
                float s = acc[m][n][reg];
                allmax = fmaxf(allmax, s);
                if ((gcol >> 3) != gi) {
                    float e = softplus(ALPHA * (s - MARGIN));
                    rm = fmaxf(rm, s);
                    if (s > th) { rs += e; rc += 1; }
                    if (!diag) {
                        colM[n] = fmaxf(colM[n], s);
                        if (s > thB[n]) { colS[n] += e; colC[n] += 1; }
                    }
                }
            }
            // reduce across the 16 col-lanes (same kgrp group)
            #pragma unroll
            for (int off = 1; off < 16; off <<= 1) {
                rs += __shfl_xor(rs, off);
                rc += __shfl_xor(rc, off);
                rm = fmaxf(rm, __shfl_xor(rm, off));
            }
            if (lrow == 0) {
                sum_part[(size_t)grow * 64 + ct] = rs;
                cnt_part[(size_t)grow * 64 + ct] = rc;
                max_part[(size_t)grow * 64 + ct] = rm;
            }
        }
    }

    if (!diag) {
        // col stats: reduce across the 4 kgrp lane-groups (lanes l, l^16, l^32, l^48)
        #pragma unroll
        for (int n = 0; n < 4; ++n) {
            float cs = colS[n], cm = colM[n];
            int cc = colC[n];
            cs += __shfl_xor(cs, 16); cs += __shfl_xor(cs, 32);
            cc += __shfl_xor(cc, 16); cc += __shfl_xor(cc, 32);
            cm = fmaxf(cm, __shfl_xor(cm, 16));
            cm = fmaxf(cm, __shfl_xor(cm, 32));
            if (kgrp == 0) {
                int gcol = C0 + n * 16 + lrow;
                sum_part[(size_t)gcol * 64 + rt] = cs;
                cnt_part[(size_t)gcol * 64 + rt] = cc;
                max_part[(size_t)gcol * 64 + rt] = cm;
            }
        }
    }

    #pragma unroll
    for (int off = 1; off < 64; off <<= 1) allmax = fmaxf(allmax, __shfl_xor(allmax, off));
    if (l == 0) atomicMax(gmax, fkey(allmax));
}

// ---------------- K3: per-row combine (64 slots, 64 lanes/row) + last-block mean ----------------
__global__ __launch_bounds__(256) void k_rowfinal(const float* __restrict__ sum_part,
                                                  const int* __restrict__ cnt_part,
                                                  const float* __restrict__ max_part,
                                                  const float* __restrict__ pos_sims,
                                                  const float* __restrict__ min_pos,
                                                  const unsigned* __restrict__ gmax,
                                                  float* __restrict__ accum,
                                                  unsigned* __restrict__ cnt,
                                                  float* __restrict__ out) {
    __shared__ float sloss[4];
    int row = blockIdx.x * 4 + (threadIdx.x >> 6);
    int lane = threadIdx.x & 63;
    float ns = sum_part[(size_t)row * 64 + lane];
    int nc = cnt_part[(size_t)row * 64 + lane];
    float nm = max_part[(size_t)row * 64 + lane];
    #pragma unroll
    for (int off = 1; off < 64; off <<= 1) {
        ns += __shfl_xor(ns, off);
        nc += __shfl_xor(nc, off);
        nm = fmaxf(nm, __shfl_xor(nm, off));
    }
    if (lane == 0) {
        float base = fmaxf(fdec(*gmax) - 0.1f, MARGIN + 0.2f);
        float neg_loss = (nc > 0) ? ns / (float)nc : softplus(ALPHA * (nm - MARGIN));
        float ps = 0.f;
        int pcnt = 0;
        float mn = min_pos[row];
        #pragma unroll
        for (int i = 0; i < NINST - 1; ++i) {
            float s = pos_sims[(size_t)row * 8 + i];
            if (s < base) { ps += softplus(-2.0f * (s - MARGIN)); pcnt++; }
        }
        float pos_loss = (pcnt > 0) ? ps / (float)pcnt : softplus(-2.0f * (mn - MARGIN));
        sloss[threadIdx.x >> 6] = pos_loss + neg_loss;
    }
    __syncthreads();
    if (threadIdx.x == 0) {
        float bs = sloss[0] + sloss[1] + sloss[2] + sloss[3];
        atomicAdd(accum, bs);
        __threadfence();
        unsigned old = atomicAdd(cnt, 1u);
        if (old == gridDim.x - 1) {
            __threadfence();
            float tot = atomicAdd(accum, 0.0f);   // final sum (all adds done)
            out[0] = tot / (float)N;
        }
    }
}

extern "C" void kernel_launch(void* const* d_in, const int* in_sizes, int n_in,
                              void* d_out, int out_size, void* d_ws, size_t ws_size,
                              hipStream_t stream) {
    const float* in = (const float*)d_in[0];
    float* out = (float*)d_out;

    char* ws = (char*)d_ws;
    ushort*  xn       = (ushort*)(ws);                          // 8 MB
    float*   min_pos  = (float*)(ws + 8388608 + 16384);         // 16 KB
    float*   pos_sims = (float*)(ws + 8388608 + 32768);         // 128 KB
    float*   sum_part = (float*)(ws + 8388608 + 32768 + 131072);            // 1 MB
    float*   max_part = (float*)(ws + 8388608 + 32768 + 131072 + 1048576);  // 1 MB
    int*     cnt_part = (int*)  (ws + 8388608 + 32768 + 131072 + 2097152);  // 1 MB
    unsigned* gmax    = (unsigned*)(ws + 8388608 + 32768 + 131072 + 3145728);
    float*   accum    = (float*)(ws + 8388608 + 32768 + 131072 + 3145728 + 64);
    unsigned* cnt     = (unsigned*)(ws + 8388608 + 32768 + 131072 + 3145728 + 128);

    k_normpos<<<NGROUP, 256, 0, stream>>>(in, xn, pos_sims, min_pos, gmax, accum, cnt);
    k_neg<<<NTILE, 64, 0, stream>>>(xn, min_pos, sum_part, cnt_part, max_part, gmax);
    k_rowfinal<<<N / 4, 256, 0, stream>>>(sum_part, cnt_part, max_part, pos_sims, min_pos,
                                          gmax, accum, cnt, out);
}